// Round 3
// baseline (531.513 us; speedup 1.0000x reference)
//
#include <hip/hip_runtime.h>
#include <hip/hip_bf16.h>

// Problem constants (CRF: B=256 seqs, M=1024 steps, D=128 feat, N=26 labels)
#define CB 256
#define CM 1024
#define CD 128
#define CN 26

__device__ inline float rfl_f(float x) {
    return __int_as_float(__builtin_amdgcn_readfirstlane(__float_as_int(x)));
}

__device__ inline float rdl_f(float x, int lane) {  // lane must be constant
    return __int_as_float(__builtin_amdgcn_readlane(__float_as_int(x), lane));
}

__device__ inline float fexp2(float x) { return exp2f(x); }
__device__ inline float flog2(float x) { return log2f(x); }

// ---------------------------------------------------------------------------
// Kernel 1: emissions E[r, a] = dot(X[r, :], W[a, :]).
// One wave per 64 rows; lane a in [0,26) owns label a. X-row addresses are
// wave-uniform -> s_load (scalar broadcast); W chunk lives in 32 VGPRs/lane.
// fma takes the X value as its single allowed SGPR operand.
// ---------------------------------------------------------------------------
__global__ __launch_bounds__(256) void emit_kernel(const float* __restrict__ X,
                                                   const float* __restrict__ W,
                                                   float* __restrict__ E) {
    const int lane = threadIdx.x & 63;
    const int wid = __builtin_amdgcn_readfirstlane(threadIdx.x >> 6);  // 0..3
    const int gw = blockIdx.x * 4 + wid;   // global wave id, 0..4095
    const int row0 = gw * 64;              // 64 rows per wave
    const int a = (lane < CN) ? lane : (CN - 1);

    for (int rc = 0; rc < 8; ++rc) {  // 8 row-chunks of 8 rows (rolled)
        const int rbase = row0 + rc * 8;
        float acc[8];
#pragma unroll
        for (int r = 0; r < 8; ++r) acc[r] = 0.f;

        for (int c = 0; c < 4; ++c) {  // 4 feature chunks of 32 (rolled)
            float wv[32];
#pragma unroll
            for (int j4 = 0; j4 < 8; ++j4) {
                float4 w4 = *reinterpret_cast<const float4*>(
                    W + a * CD + c * 32 + 4 * j4);
                wv[4 * j4 + 0] = w4.x;
                wv[4 * j4 + 1] = w4.y;
                wv[4 * j4 + 2] = w4.z;
                wv[4 * j4 + 3] = w4.w;
            }
#pragma unroll
            for (int r = 0; r < 8; ++r) {
                const float* __restrict__ xp =
                    X + (size_t)(rbase + r) * CD + c * 32;  // uniform address
                float s = acc[r];
#pragma unroll
                for (int j = 0; j < 32; ++j) s = fmaf(xp[j], wv[j], s);
                acc[r] = s;
            }
        }
        if (lane < CN) {
#pragma unroll
            for (int r = 0; r < 8; ++r)
                E[(size_t)(rbase + r) * CN + a] = acc[r];
        }
    }
}

// ---------------------------------------------------------------------------
// Kernel 2: per-sequence forward recursion in prob space + unnorm gather.
// One wave per sequence; lane a owns label a (lanes 26..63 duplicate a=25).
// Per step: f_new[a] = 2^(ge_a - c) * sum_b A[b,a] * f[b], where f[b] is
// broadcast via v_readlane (VALU/SALU path — no LDS pipe on the chain; the
// round-2 version paid TWO ds_bpermute latencies per step = 394 cyc/step).
// E stream prefetched through an 8-deep register ring (covers HBM latency).
// Renormalize by an exact power of two every 8 steps.
// ---------------------------------------------------------------------------
__global__ __launch_bounds__(64) void crf_forward_kernel(
    const float* __restrict__ E, const int* __restrict__ labels,
    const float* __restrict__ T, float* __restrict__ out) {
    const int s = blockIdx.x;
    const int l = threadIdx.x;
    const int base = s * CM;
    const float LOG2E = 1.4426950408889634f;
    const float LN2 = 0.6931471805599453f;
    const int a = (l < CN) ? l : (CN - 1);

    // ---- unnorm = sum_i e[i, y_i] + sum_i T[y_{i-1}, y_i] (all 64 lanes) ----
    float usum = 0.f;
    for (int i = l; i < CM; i += 64) {
        int y = labels[base + i];
        usum += E[(size_t)(base + i) * CN + y];
        if (i > 0) usum += T[labels[base + i - 1] * CN + y];
    }
#pragma unroll
    for (int off = 32; off > 0; off >>= 1) usum += __shfl_xor(usum, off, 64);

    // ---- transition column a, prob space: AT[b] = exp(T[b][a]) ----
    float AT[CN];
#pragma unroll
    for (int b = 0; b < CN; ++b) AT[b] = fexp2(LOG2E * T[b * CN + a]);

    // ---- init at i = 0 ----
    float ge0 = LOG2E * E[(size_t)base * CN + a];
    float c0 = rfl_f(ge0);
    float f = fexp2(ge0 - c0);
    float L = c0;

    auto step = [&](float ev) {
        float ge = LOG2E * ev;
        float c = rfl_f(ge);
        float p = fexp2(ge - c);  // off the f-chain
        float d0 = 0.f, d1 = 0.f, d2 = 0.f, d3 = 0.f;
#pragma unroll
        for (int b = 0; b < 24; b += 4) {
            d0 = fmaf(AT[b + 0], rdl_f(f, b + 0), d0);
            d1 = fmaf(AT[b + 1], rdl_f(f, b + 1), d1);
            d2 = fmaf(AT[b + 2], rdl_f(f, b + 2), d2);
            d3 = fmaf(AT[b + 3], rdl_f(f, b + 3), d3);
        }
        d0 = fmaf(AT[24], rdl_f(f, 24), d0);
        d1 = fmaf(AT[25], rdl_f(f, 25), d1);
        float d = (d0 + d1) + (d2 + d3);
        f = p * d;
        L += c;
    };

    // ---- prologue: steps i = 1..7 (loads hoist; chain not yet long) ----
#pragma unroll
    for (int i = 1; i < 8; ++i) step(E[(size_t)(base + i) * CN + a]);

    // ---- ring prefetch for steps 8..15 ----
    float ring[8];
#pragma unroll
    for (int k = 0; k < 8; ++k) ring[k] = E[(size_t)(base + 8 + k) * CN + a];

    // ---- main loop: chunks of 8 steps, i = 8..1023 ----
    for (int i0 = 8; i0 + 8 <= CM; i0 += 8) {
#pragma unroll
        for (int k = 0; k < 8; ++k) {
            float ev = ring[k];
            int nidx = i0 + 8 + k;
            if (nidx > CM - 1) nidx = CM - 1;                 // clamped dummy
            ring[k] = E[(size_t)(base + nidx) * CN + a];      // prefetch
            step(ev);
            if (k == 7) {  // i = i0+7 ... renorm after every 8th step
                float fr = rfl_f(f);
                int k2 = (int)((__float_as_uint(fr) >> 23) & 255) - 127;
                f = ldexpf(f, -k2);  // exact power-of-2: no rounding
                L += (float)k2;
            }
        }
    }

    // ---- logZ = ln2 * (L + log2(sum_a f[a])) ----
    float fv = (l < CN) ? f : 0.f;
#pragma unroll
    for (int off = 32; off > 0; off >>= 1) fv += __shfl_xor(fv, off, 64);
    float logZ = LN2 * (L + flog2(fv));

    if (l == 0) atomicAdd(out, (usum - logZ) * (1.f / (float)CB));
}

extern "C" void kernel_launch(void* const* d_in, const int* in_sizes, int n_in,
                              void* d_out, int out_size, void* d_ws,
                              size_t ws_size, hipStream_t stream) {
    const float* X = (const float*)d_in[0];   // [B, M, D]
    const int* labels = (const int*)d_in[1];  // [B, M]
    const float* W = (const float*)d_in[2];   // [N, D]
    const float* T = (const float*)d_in[3];   // [N, N]
    float* out = (float*)d_out;               // scalar
    float* E = (float*)d_ws;                  // [B*M, N] emissions

    hipMemsetAsync(d_out, 0, sizeof(float), stream);
    emit_kernel<<<(CB * CM) / 256, 256, 0, stream>>>(X, W, E);
    crf_forward_kernel<<<CB, 64, 0, stream>>>(E, labels, T, out);
}

// Round 4
// 494.517 us; speedup vs baseline: 1.0748x; 1.0748x over previous
//
#include <hip/hip_runtime.h>

// CRF: B=256 seqs, M=1024 steps, D=128 feat, N=26 labels
#define CB 256
#define CM 1024
#define CD 128
#define CN 26

#define EPAD 27    // E row stride in LDS f32 (odd -> conflict-free lane reads)
#define XSTRIDE 257  // transposed X stage: XS[feat][row], odd stride

__device__ inline float rfl_f(float x) {
    return __int_as_float(__builtin_amdgcn_readfirstlane(__float_as_int(x)));
}

// ---------------------------------------------------------------------------
// One block per sequence. Phase 1: emissions E[i][a] = X[i,:].W[a,:] into LDS
// (X coalesced->LDS transpose; W via scalar cache as the fma SGPR operand).
// Phase 2: wave 0 runs the forward chain (13 ds_bpermute + DPP pair-combine),
// wave 1 concurrently computes the unnormalized score. E never touches HBM.
// ---------------------------------------------------------------------------
__global__ __launch_bounds__(256, 1) void crf_fused(
    const float* __restrict__ X, const int* __restrict__ labels,
    const float* __restrict__ W, const float* __restrict__ T,
    float* __restrict__ out) {
    __shared__ float E[(CM + 4) * EPAD];   // 111,024 B (+4 pad rows for ring)
    __shared__ float XS[32 * XSTRIDE];     //  32,896 B

    const int t = threadIdx.x;
    const int s = blockIdx.x;
    const float LOG2E = 1.4426950408889634f;
    const float LN2 = 0.6931471805599453f;
    const float* __restrict__ Xs = X + (size_t)s * CM * CD;

    // ---------------- Phase 1: emissions into LDS ----------------
    for (int rc = 0; rc < 4; ++rc) {       // 4 chunks of 256 rows
        float acc[CN];
#pragma unroll
        for (int a = 0; a < CN; ++a) acc[a] = 0.f;

        for (int kc = 0; kc < 4; ++kc) {   // 4 chunks of 32 features
            __syncthreads();               // previous XS readers done
            // stage 256 rows x 32 feats, global-coalesced, LDS-transposed
#pragma unroll
            for (int i = 0; i < 8; ++i) {
                int id = i * 256 + t;      // 2048 float4
                int row = id >> 3, j4 = id & 7;
                float4 v = *reinterpret_cast<const float4*>(
                    Xs + (size_t)(rc * 256 + row) * CD + kc * 32 + j4 * 4);
                XS[(j4 * 4 + 0) * XSTRIDE + row] = v.x;
                XS[(j4 * 4 + 1) * XSTRIDE + row] = v.y;
                XS[(j4 * 4 + 2) * XSTRIDE + row] = v.z;
                XS[(j4 * 4 + 3) * XSTRIDE + row] = v.w;
            }
            __syncthreads();               // staging visible

            float x[32];                   // this thread's row (row = t)
#pragma unroll
            for (int j = 0; j < 32; ++j) x[j] = XS[j * XSTRIDE + t];

            const float* __restrict__ Wc = W + kc * 32;  // uniform -> s_load
#pragma unroll
            for (int a = 0; a < CN; ++a) {
                float sum = acc[a];
#pragma unroll
                for (int j = 0; j < 32; ++j)
                    sum = fmaf(x[j], Wc[a * CD + j], sum);
                acc[a] = sum;
            }
        }
        const int r_abs = rc * 256 + t;
#pragma unroll
        for (int a = 0; a < CN; ++a) E[r_abs * EPAD + a] = acc[a];
    }
    __syncthreads();  // E complete; waves diverge below (no more barriers)

    const int wave = t >> 6;

    if (wave == 1) {
        // ---------------- unnorm score (runs parallel to the chain) --------
        const int l = t & 63;
        float usum = 0.f;
        for (int i = l; i < CM; i += 64) {
            int y = labels[s * CM + i];
            usum += E[i * EPAD + y];
            if (i > 0) usum += T[labels[s * CM + i - 1] * CN + y];
        }
#pragma unroll
        for (int off = 32; off > 0; off >>= 1)
            usum += __shfl_xor(usum, off, 64);
        if (l == 0) atomicAdd(out, usum * (1.f / (float)CB));
    } else if (wave == 0) {
        // ---------------- forward chain --------------------------------
        const int l = t;
        const bool lact = (l < 2 * CN);          // lanes 0..51 active
        const int a = lact ? (l >> 1) : (CN - 1);
        const int hh = lact ? (l & 1) : 1;       // which half of the b-sum

        float AT[13];
        int ba[13];  // bpermute byte-addresses of source lanes (static)
#pragma unroll
        for (int k = 0; k < 13; ++k) {
            int b = hh * 13 + k;
            AT[k] = expf(T[b * CN + a]);
            ba[k] = 4 * (2 * b);                 // f[b] lives at lane 2b
        }

        float ge0 = LOG2E * E[a];
        float c0 = rfl_f(ge0);
        float f = exp2f(ge0 - c0);
        float L = c0;

        float ring[4];
#pragma unroll
        for (int k = 0; k < 4; ++k) ring[k] = E[(1 + k) * EPAD + a];

        for (int i = 1; i < CM; ++i) {
            float ev = ring[(i - 1) & 3];
            ring[(i - 1) & 3] = E[(i + 4) * EPAD + a];  // prefetch (padded)

            float ge = LOG2E * ev;
            float c = rfl_f(ge);
            float p = exp2f(ge - c);             // off the f-chain

            int fi = __float_as_int(f);
            float d0 = 0.f, d1 = 0.f, d2 = 0.f, d3 = 0.f;
#pragma unroll
            for (int k = 0; k < 12; k += 4) {
                d0 = fmaf(AT[k + 0], __int_as_float(__builtin_amdgcn_ds_bpermute(ba[k + 0], fi)), d0);
                d1 = fmaf(AT[k + 1], __int_as_float(__builtin_amdgcn_ds_bpermute(ba[k + 1], fi)), d1);
                d2 = fmaf(AT[k + 2], __int_as_float(__builtin_amdgcn_ds_bpermute(ba[k + 2], fi)), d2);
                d3 = fmaf(AT[k + 3], __int_as_float(__builtin_amdgcn_ds_bpermute(ba[k + 3], fi)), d3);
            }
            d0 = fmaf(AT[12], __int_as_float(__builtin_amdgcn_ds_bpermute(ba[12], fi)), d0);
            float d = (d0 + d1) + (d2 + d3);

            // pair-combine via DPP quad_perm [1,0,3,2] — VALU, no DS latency
            int sw = __builtin_amdgcn_update_dpp(0, __float_as_int(d),
                                                 0xB1, 0xF, 0xF, true);
            d = d + __int_as_float(sw);

            f = p * d;
            L += c;

            if ((i & 7) == 0) {  // exact power-of-2 renorm, no rounding
                float fr = rfl_f(f);
                int k2 = (int)((__float_as_uint(fr) >> 23) & 255) - 127;
                f = ldexpf(f, -k2);
                L += (float)k2;
            }
        }

        float fv = (lact && hh == 0) ? f : 0.f;  // one copy per label
#pragma unroll
        for (int off = 32; off > 0; off >>= 1) fv += __shfl_xor(fv, off, 64);
        float logZ = LN2 * (L + log2f(fv));
        if (l == 0) atomicAdd(out, -logZ * (1.f / (float)CB));
    }
}

extern "C" void kernel_launch(void* const* d_in, const int* in_sizes, int n_in,
                              void* d_out, int out_size, void* d_ws,
                              size_t ws_size, hipStream_t stream) {
    const float* X = (const float*)d_in[0];   // [B, M, D]
    const int* labels = (const int*)d_in[1];  // [B, M]
    const float* W = (const float*)d_in[2];   // [N, D]
    const float* T = (const float*)d_in[3];   // [N, N]
    float* out = (float*)d_out;               // scalar

    hipMemsetAsync(d_out, 0, sizeof(float), stream);
    crf_fused<<<CB, 256, 0, stream>>>(X, labels, W, T, out);
}